// Round 9
// baseline (120.836 us; speedup 1.0000x reference)
//
#include <hip/hip_runtime.h>

// Problem constants
#define NB   16
#define CIN  256
#define COUT 256
#define HH   32
#define WW   32
#define HW   1024           // 32*32
#define KK   9
#define CK   2304           // CIN*KK  (ordered k*256 + c, tap-major)

typedef __bf16 bf16x8 __attribute__((ext_vector_type(8)));
typedef float  f32x4  __attribute__((ext_vector_type(4)));

__device__ __forceinline__ unsigned short f2bf(float f) {
    unsigned int u = __float_as_uint(f);
    u += 0x7FFFu + ((u >> 16) & 1u);          // round-nearest-even
    return (unsigned short)(u >> 16);
}
__device__ __forceinline__ float bfhi(unsigned int u) {   // high bf16 -> f32
    return __uint_as_float(u & 0xFFFF0000u);
}
__device__ __forceinline__ float bflo(unsigned int u) {   // low bf16 -> f32
    return __uint_as_float(u << 16);
}
// pack two f32 -> one dword of 2x bf16 (RNE). No builtin on gfx950 (ROCm 7.2)
// — inline asm v_cvt_pk_bf16_f32: src0 -> low 16, src1 -> high 16.
__device__ __forceinline__ unsigned pk2(float lo, float hi) {
    unsigned r;
    asm("v_cvt_pk_bf16_f32 %0, %1, %2" : "=v"(r) : "v"(lo), "v"(hi));
    return r;
}

#define SB() __builtin_amdgcn_sched_barrier(0)
// Barrier: LDS-visibility only (B ds_write -> next step's frag reads).
// All VMEM destinations are REGISTERS in this version (no global_load_lds),
// so the compiler emits exact counted vmcnt waits itself — no manual vmcnt.
#define SYNC() do { SB(); asm volatile("s_waitcnt lgkmcnt(0)" ::: "memory"); SB(); \
                    __builtin_amdgcn_s_barrier(); SB(); } while (0)

// ----------------------------------------------------------------- prep ----
// One kernel, two roles (saves a launch and runs them concurrently):
//   blocks [0,256):    weight fp32 [O][C][3][3] -> bf16 [O][k*256+c]
//   blocks [256,1280): x fp32 [n][c][hw] -> xtb bf16 [n][hw][c] (64x64 tiles)
// Grid-barrier mono fusion measured WORSE (round 3) — keep two dispatches.
__global__ __launch_bounds__(256) void prep_kernel(const float* __restrict__ w,
                                                   unsigned short* __restrict__ wbf,
                                                   const float* __restrict__ x,
                                                   unsigned short* __restrict__ xtb) {
    __shared__ float lsbuf[64 * 65];
    const int t = threadIdx.x;

    if (blockIdx.x < 256) {
        // ---- wconv role
        const int o = blockIdx.x;
        const float* wo = w + (size_t)o * CK;
#pragma unroll
        for (int i = t; i < CK; i += 256) lsbuf[i] = wo[i];
        __syncthreads();
        unsigned short* dst = wbf + (size_t)o * CK;
#pragma unroll
        for (int i = t; i < CK; i += 256) {
            int k = i >> 8, c = i & 255;
            dst[i] = f2bf(lsbuf[c * KK + k]);     // bank stride 9: conflict-free
        }
        return;
    }

    // ---- xt role
    float (*ls)[65] = (float(*)[65])lsbuf;
    const int id  = blockIdx.x - 256;
    const int c0  = (id & 3) << 6;
    const int hw0 = ((id >> 2) & 15) << 6;
    const int n   = id >> 6;
    {
        int c = t >> 2, q = t & 3;
        const float4* base = (const float4*)(x + ((size_t)(n * CIN + c0 + c)) * HW + hw0 + q * 16);
#pragma unroll
        for (int j = 0; j < 4; ++j) {
            float4 v = base[j];
            ls[c][q * 16 + j * 4 + 0] = v.x;
            ls[c][q * 16 + j * 4 + 1] = v.y;
            ls[c][q * 16 + j * 4 + 2] = v.z;
            ls[c][q * 16 + j * 4 + 3] = v.w;
        }
    }
    __syncthreads();
    {
        int hw = t >> 2, seg = (t & 3) * 16;
        unsigned int dw[8];
#pragma unroll
        for (int j = 0; j < 8; ++j) {
            float f0 = ls[seg + 2 * j][hw];
            float f1 = ls[seg + 2 * j + 1][hw];
            dw[j] = (unsigned)f2bf(f0) | ((unsigned)f2bf(f1) << 16);
        }
        uint4* dst = (uint4*)(xtb + ((size_t)(n * HW + hw0 + hw)) * CIN + c0 + seg);
        dst[0] = *(uint4*)&dw[0];
        dst[1] = *(uint4*)&dw[4];
    }
}

// ---------------------------------------------------------------- fused ----
// BM=256, BN=64, BK=64, 36 steps (round-6 structure — best measured, 0 bank
// conflicts; BK=128 measured WORSE twice, 3.5-4.1M conflicts, abandoned).
//
// Round-9 change: A-operand (weights) goes GLOBAL->VGPR directly, skipping
// LDS entirely. A-frags are per-wave-private (no cross-wave reuse), the
// weight matrix is L2-resident per XCD (all 16 blocks of an image share one
// XCD via the id decode), and the fragment loads coalesce as 16 rows x 64 B.
// Ping-pong afA/afB register sets give a one-step prefetch (~2300 cyc slack
// vs ~200 cyc L2 latency). This removes the As triple-buffer (LDS 112->16
// KB), the DMA LDS-port traffic (~500 cyc/step), and ALL manual vmcnt
// machinery (every VMEM dest is a register -> compiler-exact counted waits).
// Bs double-buffered, lerped one step ahead from corner regs gathered one
// step earlier. Raw barrier = lgkmcnt(0) + s_barrier. setprio around MFMA.
__global__ __launch_bounds__(512, 2) void fused_kernel(const unsigned short* __restrict__ wbf,
                                                       const unsigned short* __restrict__ xtb,
                                                       const float* __restrict__ off,
                                                       float* __restrict__ out) {
    __shared__ unsigned short Bs[2][64 * 64];    // 16 KB total

    const int tid  = threadIdx.x;
    const int wv   = tid >> 6;                // 0..7  (M position, 32 rows each)
    const int lane = tid & 63;
    const int quad = lane >> 4;
    const int l15  = lane & 15;

    const int hw_local = tid >> 3;            // 0..63
    const int seg      = tid & 7;             // 8-channel segment within 64

    // XCD-aware decode (gfx950 dispatch: consecutive ids round-robin XCDs)
    const int id  = blockIdx.x;
    const int n   = ((id & 7) << 1) | ((id >> 3) & 1);
    const int hw0 = (id >> 4) * 64;

    const int hw = hw0 + hw_local;
    const int h  = hw >> 5, w = hw & 31;

    const uint4*  xb4  = (const uint4*)(xtb + (size_t)n * HW * CIN);
    const float2* offp = (const float2*)(off + ((size_t)n * HW + hw) * (2 * KK));

    f32x4 acc[2][4] = {};

    auto setup2 = [&](float2 o, int tapv, float* wg, int* ix) {
        float py = (float)(h + tapv / 3 - 1) + o.x;
        float px = (float)(w + tapv % 3 - 1) + o.y;
        float y0f = floorf(py), x0f = floorf(px);
        float ly = py - y0f, lx = px - x0f;
        int y0 = (int)y0f, x0 = (int)x0f;
#pragma unroll
        for (int c2 = 0; c2 < 4; ++c2) {
            int yy = y0 + (c2 >> 1);
            int xx = x0 + (c2 & 1);
            float wy = (c2 >> 1) ? ly : 1.0f - ly;
            float wx = (c2 & 1) ? lx : 1.0f - lx;
            bool v = (yy >= 0) && (yy < HH) && (xx >= 0) && (xx < WW);
            wg[c2] = v ? wy * wx : 0.0f;
            int yc = yy < 0 ? 0 : (yy > HH - 1 ? HH - 1 : yy);
            int xc = xx < 0 ? 0 : (xx > WW - 1 ? WW - 1 : xx);
            ix[c2] = yc * WW + xc;
        }
    };

    auto loadc = [&](uint4 cr[4], const int* ix, int q) {
#pragma unroll
        for (int c2 = 0; c2 < 4; ++c2)
            cr[c2] = xb4[(size_t)ix[c2] * 32 + q * 8 + seg];
    };

    // A-fragments for k-block s, straight from global (L2-hot weights).
    // Per instr: lanes (quad,l15) read 16 rows x 4 consecutive 16B chunks
    // -> 16 x 64B coalesced lines.
    auto loadA = [&](bf16x8 af[2][2], int s) {
#pragma unroll
        for (int mi = 0; mi < 2; ++mi)
#pragma unroll
            for (int hh = 0; hh < 2; ++hh) {
                int row = wv * 32 + mi * 16 + l15;
                af[mi][hh] = *(const bf16x8*)(wbf + (size_t)row * CK + s * 64 + (hh * 4 + quad) * 8);
            }
    };

    auto lerpB = [&](int bi, const uint4 cr[4], const float* wg) {
        unsigned u0[4], u1[4], u2[4], u3[4];
        *(uint4*)u0 = cr[0]; *(uint4*)u1 = cr[1];
        *(uint4*)u2 = cr[2]; *(uint4*)u3 = cr[3];
        unsigned dw[4];
#pragma unroll
        for (int d = 0; d < 4; ++d) {
            float lo = wg[0] * bflo(u0[d]) + wg[1] * bflo(u1[d])
                     + wg[2] * bflo(u2[d]) + wg[3] * bflo(u3[d]);
            float hi = wg[0] * bfhi(u0[d]) + wg[1] * bfhi(u1[d])
                     + wg[2] * bfhi(u2[d]) + wg[3] * bfhi(u3[d]);
            dw[d] = pk2(lo, hi);              // v_cvt_pk_bf16_f32 (RNE)
        }
        *(uint4*)&Bs[bi][hw_local * 64 + (seg ^ (hw_local & 7)) * 8] = *(uint4*)dw;
    };

    // B frag reads: 8 ds_read_b128 (conflict-free, measured round 6)
    auto frag_readB = [&](int bi, bf16x8 bfr[4][2]) {
        const unsigned short* Bp = &Bs[bi][0];
#pragma unroll
        for (int ni = 0; ni < 4; ++ni)
#pragma unroll
            for (int hh = 0; hh < 2; ++hh) {
                int row = ni * 16 + l15;
                int ch  = (hh * 4 + quad) ^ (row & 7);
                bfr[ni][hh] = *(const bf16x8*)(Bp + row * 64 + ch * 8);
            }
    };

    auto frag_mma = [&](bf16x8 af[2][2], bf16x8 bfr[4][2]) {
        __builtin_amdgcn_s_setprio(1);
#pragma unroll
        for (int mi = 0; mi < 2; ++mi)
#pragma unroll
            for (int ni = 0; ni < 4; ++ni) {
                acc[mi][ni] = __builtin_amdgcn_mfma_f32_16x16x32_bf16(af[mi][0], bfr[ni][0], acc[mi][ni], 0, 0, 0);
                acc[mi][ni] = __builtin_amdgcn_mfma_f32_16x16x32_bf16(af[mi][1], bfr[ni][1], acc[mi][ni], 0, 0, 0);
            }
        __builtin_amdgcn_s_setprio(0);
    };

    // ---- prologue: afA <- A(0), Bs[0] <- lerp(k0), crB holds k1 corners
    float wgc[4], wgn[4];
    int   ixc[4], ixn[4];
    uint4 crA[4], crB[4];
    bf16x8 afA[2][2], afB[2][2];
    {
        float2 o0 = offp[0];
        setup2(o0, 0, wgc, ixc);
        loadA(afA, 0);
        SB();
        loadc(crA, ixc, 0);
        SB();
        lerpB(0, crA, wgc);   // vmcnt wait on crA also drains afA (older) — fine
        SB();
        loadc(crB, ixc, 1);
        SYNC();
    }

    // ---- main loop: step s = tap*4+q. mma reads af{A,B} (by parity) and
    // Bs[s&1]; loadA prefetches A(s+1) into the other af set; lerp fills
    // Bs[(s+1)&1] from cr gathered one step earlier.
#pragma unroll 1
    for (int tap = 0; tap < 9; ++tap) {
        const int kb = tap * 4;
        const bool more = (tap < 8);
        bf16x8 bfr[4][2];

        // q0 (s=kb): af=afA, Bs[0]
        frag_readB(0, bfr);
        SB();
        loadA(afB, kb + 1);
        SB();
        lerpB(1, crB, wgc);
        SB();
        loadc(crA, ixc, 2);
        SB();
        frag_mma(afA, bfr);
        SYNC();

        // q1 (s=kb+1): af=afB, Bs[1]
        frag_readB(1, bfr);
        SB();
        loadA(afA, kb + 2);
        SB();
        lerpB(0, crA, wgc);
        SB();
        loadc(crB, ixc, 3);
        SB();
        frag_mma(afB, bfr);
        SYNC();

        // q2 (s=kb+2): af=afA, Bs[0]; offp prefetch at head (L2-hot)
        float2 onx = {};
        if (more) onx = offp[tap + 1];
        SB();
        frag_readB(0, bfr);
        SB();
        loadA(afB, kb + 3);
        SB();
        lerpB(1, crB, wgc);
        SB();
        if (more) { setup2(onx, tap + 1, wgn, ixn); loadc(crA, ixn, 0); }
        SB();
        frag_mma(afA, bfr);
        SYNC();

        // q3 (s=kb+3): af=afB, Bs[1]
        frag_readB(1, bfr);
        SB();
        if (more) {
            loadA(afA, kb + 4);
            SB();
            lerpB(0, crA, wgn);
            SB();
            loadc(crB, ixn, 1);
#pragma unroll
            for (int c2 = 0; c2 < 4; ++c2) { wgc[c2] = wgn[c2]; ixc[c2] = ixn[c2]; }
            SB();
            frag_mma(afB, bfr);
            SYNC();
        } else {
            frag_mma(afB, bfr);      // last step, no barrier needed after
        }
    }

    // ---- epilogue: D layout col = lane&15, row = quad*4 + reg
    float* opnt = out + (size_t)n * COUT * HW + hw0;
#pragma unroll
    for (int mi = 0; mi < 2; ++mi)
#pragma unroll
        for (int ni = 0; ni < 4; ++ni) {
            int col = ni * 16 + l15;
#pragma unroll
            for (int rr = 0; rr < 4; ++rr) {
                int row = wv * 32 + mi * 16 + quad * 4 + rr;
                opnt[(size_t)row * HW + col] = acc[mi][ni][rr];
            }
        }
}

// --------------------------------------------------------------- launch ----
extern "C" void kernel_launch(void* const* d_in, const int* in_sizes, int n_in,
                              void* d_out, int out_size, void* d_ws, size_t ws_size,
                              hipStream_t stream) {
    const float* x   = (const float*)d_in[0];   // [16][256][32][32]
    const float* off = (const float*)d_in[1];   // [16][1024][18]
    const float* wt  = (const float*)d_in[2];   // [256][256][3][3]
    float* out = (float*)d_out;                 // [16][256][32][32]

    unsigned short* wbf = (unsigned short*)d_ws;                        // 1179648 B
    unsigned short* xtb = (unsigned short*)((char*)d_ws + 1179648);     // 8388608 B

    prep_kernel<<<1280, 256, 0, stream>>>(wt, wbf, x, xtb);
    fused_kernel<<<256, 512, 0, stream>>>(wbf, xtb, off, out);
}

// Round 10
// 115.501 us; speedup vs baseline: 1.0462x; 1.0462x over previous
//
#include <hip/hip_runtime.h>

// Problem constants
#define NB   16
#define CIN  256
#define COUT 256
#define HH   32
#define WW   32
#define HW   1024           // 32*32
#define KK   9
#define CK   2304           // CIN*KK  (ordered k*256 + c, tap-major)

typedef __bf16 bf16x8 __attribute__((ext_vector_type(8)));
typedef float  f32x4  __attribute__((ext_vector_type(4)));

__device__ __forceinline__ unsigned short f2bf(float f) {
    unsigned int u = __float_as_uint(f);
    u += 0x7FFFu + ((u >> 16) & 1u);          // round-nearest-even
    return (unsigned short)(u >> 16);
}
__device__ __forceinline__ float bfhi(unsigned int u) {   // high bf16 -> f32
    return __uint_as_float(u & 0xFFFF0000u);
}
__device__ __forceinline__ float bflo(unsigned int u) {   // low bf16 -> f32
    return __uint_as_float(u << 16);
}
// pack two f32 -> one dword of 2x bf16 (RNE). No builtin on gfx950 (ROCm 7.2)
// — inline asm v_cvt_pk_bf16_f32: src0 -> low 16, src1 -> high 16.
__device__ __forceinline__ unsigned pk2(float lo, float hi) {
    unsigned r;
    asm("v_cvt_pk_bf16_f32 %0, %1, %2" : "=v"(r) : "v"(lo), "v"(hi));
    return r;
}

typedef const __attribute__((address_space(1))) void* gas_ptr;
typedef __attribute__((address_space(3))) void* las_ptr;

__device__ __forceinline__ void async16(const void* g, void* l) {
    __builtin_amdgcn_global_load_lds((gas_ptr)g, (las_ptr)l, 16, 0, 0);
}

#define SB() __builtin_amdgcn_sched_barrier(0)
// Raw barrier: LDS-visibility only. A-DMA completion uses the counted vmcnt
// at superstep entry (below) — vmcnt is never drained to 0 mid-loop.
#define SYNC() do { SB(); asm volatile("s_waitcnt lgkmcnt(0)" ::: "memory"); SB(); \
                    __builtin_amdgcn_s_barrier(); SB(); } while (0)
// Counted VMEM waits (T4). Superstep-entry outstanding:
//  A-entry: dma(8) + gathers crC,crD(8) + [offv(1) if present] -> vmcnt(8)
//           drains the 8 DMAs (+ at most one week-old gather — harmless).
//  B-entry: dma(8) + gathers crA,crB(8) = 16 -> vmcnt(8) exact.
//  Final B: only dma(8) outstanding -> vmcnt(0).
#define VM8() do { SB(); asm volatile("s_waitcnt vmcnt(8)" ::: "memory"); SB(); } while (0)
#define VM0() do { SB(); asm volatile("s_waitcnt vmcnt(0)" ::: "memory"); SB(); } while (0)

// ----------------------------------------------------------------- prep ----
// One kernel, two roles (saves a launch and runs them concurrently):
//   blocks [0,256):    weight fp32 [O][C][3][3] -> bf16 [O][k*256+c]
//   blocks [256,1280): x fp32 [n][c][hw] -> xtb bf16 [n][hw][c] (64x64 tiles)
// Grid-barrier mono fusion measured WORSE (round 3) — keep two dispatches.
__global__ __launch_bounds__(256) void prep_kernel(const float* __restrict__ w,
                                                   unsigned short* __restrict__ wbf,
                                                   const float* __restrict__ x,
                                                   unsigned short* __restrict__ xtb) {
    __shared__ float lsbuf[64 * 65];
    const int t = threadIdx.x;

    if (blockIdx.x < 256) {
        // ---- wconv role
        const int o = blockIdx.x;
        const float* wo = w + (size_t)o * CK;
#pragma unroll
        for (int i = t; i < CK; i += 256) lsbuf[i] = wo[i];
        __syncthreads();
        unsigned short* dst = wbf + (size_t)o * CK;
#pragma unroll
        for (int i = t; i < CK; i += 256) {
            int k = i >> 8, c = i & 255;
            dst[i] = f2bf(lsbuf[c * KK + k]);     // bank stride 9: conflict-free
        }
        return;
    }

    // ---- xt role
    float (*ls)[65] = (float(*)[65])lsbuf;
    const int id  = blockIdx.x - 256;
    const int c0  = (id & 3) << 6;
    const int hw0 = ((id >> 2) & 15) << 6;
    const int n   = id >> 6;
    {
        int c = t >> 2, q = t & 3;
        const float4* base = (const float4*)(x + ((size_t)(n * CIN + c0 + c)) * HW + hw0 + q * 16);
#pragma unroll
        for (int j = 0; j < 4; ++j) {
            float4 v = base[j];
            ls[c][q * 16 + j * 4 + 0] = v.x;
            ls[c][q * 16 + j * 4 + 1] = v.y;
            ls[c][q * 16 + j * 4 + 2] = v.z;
            ls[c][q * 16 + j * 4 + 3] = v.w;
        }
    }
    __syncthreads();
    {
        int hw = t >> 2, seg = (t & 3) * 16;
        unsigned int dw[8];
#pragma unroll
        for (int j = 0; j < 8; ++j) {
            float f0 = ls[seg + 2 * j][hw];
            float f1 = ls[seg + 2 * j + 1][hw];
            dw[j] = (unsigned)f2bf(f0) | ((unsigned)f2bf(f1) << 16);
        }
        uint4* dst = (uint4*)(xtb + ((size_t)(n * HW + hw0 + hw)) * CIN + c0 + seg);
        dst[0] = *(uint4*)&dw[0];
        dst[1] = *(uint4*)&dw[4];
    }
}

// ---------------------------------------------------------------- fused ----
// BM=256, BN=64, BK=64 — round-6 access patterns EXACTLY (best measured,
// 0 bank conflicts; every LDS row stays 128 B — the 256 B-row BK=128
// variants measured 3.5-4.1M conflicts; A-from-global measured +9 us of
// exposed L2 latency; both abandoned).
//
// Round-10 change: SUPERSTEP = 2 k-blocks per barrier (18 barriers, was
// 36). As: 4 x [256x64] buffers (k-block s -> buffer s%4), DMA'd one
// superstep ahead, drained by counted vmcnt(8) at entry. Bs: 4 x [64x64],
// lerped one superstep ahead (corners gathered one superstep before that).
// LDS = 128 + 32 = 160 KiB exactly. Superstep A of tap t: mma k(4t),k(4t+1),
// DMA k(4t+2,4t+3), lerp Bs for them (tap-t quarters 2,3), gather quarters
// 0,1 of tap t+1. Superstep B: mma k(4t+2),k(4t+3), DMA k(4t+4,4t+5), lerp
// quarters 0,1 of tap t+1, gather quarters 2,3 of tap t+1.
__global__ __launch_bounds__(512, 2) void fused_kernel(const unsigned short* __restrict__ wbf,
                                                       const unsigned short* __restrict__ xtb,
                                                       const float* __restrict__ off,
                                                       float* __restrict__ out) {
    __shared__ unsigned short As[4][256 * 64];   // 128 KB
    __shared__ unsigned short Bs[4][64 * 64];    // 32 KB

    const int tid  = threadIdx.x;
    const int wv   = tid >> 6;                // 0..7  (M position, 32 rows each)
    const int lane = tid & 63;
    const int quad = lane >> 4;
    const int l15  = lane & 15;

    const int hw_local = tid >> 3;            // 0..63
    const int seg      = tid & 7;             // 8-channel segment within 64

    // XCD-aware decode (gfx950 dispatch: consecutive ids round-robin XCDs)
    const int id  = blockIdx.x;
    const int n   = ((id & 7) << 1) | ((id >> 3) & 1);
    const int hw0 = (id >> 4) * 64;

    const int hw = hw0 + hw_local;
    const int h  = hw >> 5, w = hw & 31;

    // A staging lane pattern (XOR swizzle encoded in source address)
    const int srow   = lane >> 3;
    const int schunk = (lane & 7) ^ (srow & 7);

    const uint4*  xb4  = (const uint4*)(xtb + (size_t)n * HW * CIN);
    const float2* offp = (const float2*)(off + ((size_t)n * HW + hw) * (2 * KK));

    f32x4 acc[2][4] = {};

    auto setup2 = [&](float2 o, int tapv, float* wg, int* ix) {
        float py = (float)(h + tapv / 3 - 1) + o.x;
        float px = (float)(w + tapv % 3 - 1) + o.y;
        float y0f = floorf(py), x0f = floorf(px);
        float ly = py - y0f, lx = px - x0f;
        int y0 = (int)y0f, x0 = (int)x0f;
#pragma unroll
        for (int c2 = 0; c2 < 4; ++c2) {
            int yy = y0 + (c2 >> 1);
            int xx = x0 + (c2 & 1);
            float wy = (c2 >> 1) ? ly : 1.0f - ly;
            float wx = (c2 & 1) ? lx : 1.0f - lx;
            bool v = (yy >= 0) && (yy < HH) && (xx >= 0) && (xx < WW);
            wg[c2] = v ? wy * wx : 0.0f;
            int yc = yy < 0 ? 0 : (yy > HH - 1 ? HH - 1 : yy);
            int xc = xx < 0 ? 0 : (xx > WW - 1 ? WW - 1 : xx);
            ix[c2] = yc * WW + xc;
        }
    };

    auto loadc = [&](uint4 cr[4], const int* ix, int q) {
#pragma unroll
        for (int c2 = 0; c2 < 4; ++c2)
            cr[c2] = xb4[(size_t)ix[c2] * 32 + q * 8 + seg];
    };

    // DMA one 256x64 A tile (k-block kblk) into As[ai] — round-6 pattern
    auto dmaA = [&](int ai, int kblk) {
        const unsigned short* wsrc = wbf + (size_t)kblk * 64 + (size_t)srow * CK + schunk * 8;
        unsigned short* dst = &As[ai][0];
#pragma unroll
        for (int j = 0; j < 4; ++j) {
            int rb = wv * 32 + j * 8;
            async16(wsrc + (size_t)rb * CK, dst + rb * 64);
        }
    };

    auto lerpB = [&](int bi, const uint4 cr[4], const float* wg) {
        unsigned u0[4], u1[4], u2[4], u3[4];
        *(uint4*)u0 = cr[0]; *(uint4*)u1 = cr[1];
        *(uint4*)u2 = cr[2]; *(uint4*)u3 = cr[3];
        unsigned dw[4];
#pragma unroll
        for (int d = 0; d < 4; ++d) {
            float lo = wg[0] * bflo(u0[d]) + wg[1] * bflo(u1[d])
                     + wg[2] * bflo(u2[d]) + wg[3] * bflo(u3[d]);
            float hi = wg[0] * bfhi(u0[d]) + wg[1] * bfhi(u1[d])
                     + wg[2] * bfhi(u2[d]) + wg[3] * bfhi(u3[d]);
            dw[d] = pk2(lo, hi);              // v_cvt_pk_bf16_f32 (RNE)
        }
        *(uint4*)&Bs[bi][hw_local * 64 + (seg ^ (hw_local & 7)) * 8] = *(uint4*)dw;
    };

    // issue the 12 frag ds_reads (compiler places lgkmcnt before MFMA uses)
    auto frag_read = [&](int ai, int bi, bf16x8 af[2][2], bf16x8 bfr[4][2]) {
        const unsigned short* Ap = &As[ai][0];
        const unsigned short* Bp = &Bs[bi][0];
#pragma unroll
        for (int mi = 0; mi < 2; ++mi)
#pragma unroll
            for (int hh = 0; hh < 2; ++hh) {
                int row = wv * 32 + mi * 16 + l15;
                int ch  = (hh * 4 + quad) ^ (row & 7);
                af[mi][hh] = *(const bf16x8*)(Ap + row * 64 + ch * 8);
            }
#pragma unroll
        for (int ni = 0; ni < 4; ++ni)
#pragma unroll
            for (int hh = 0; hh < 2; ++hh) {
                int row = ni * 16 + l15;
                int ch  = (hh * 4 + quad) ^ (row & 7);
                bfr[ni][hh] = *(const bf16x8*)(Bp + row * 64 + ch * 8);
            }
    };

    auto frag_mma = [&](bf16x8 af[2][2], bf16x8 bfr[4][2]) {
        __builtin_amdgcn_s_setprio(1);
#pragma unroll
        for (int mi = 0; mi < 2; ++mi)
#pragma unroll
            for (int ni = 0; ni < 4; ++ni) {
                acc[mi][ni] = __builtin_amdgcn_mfma_f32_16x16x32_bf16(af[mi][0], bfr[ni][0], acc[mi][ni], 0, 0, 0);
                acc[mi][ni] = __builtin_amdgcn_mfma_f32_16x16x32_bf16(af[mi][1], bfr[ni][1], acc[mi][ni], 0, 0, 0);
            }
        __builtin_amdgcn_s_setprio(0);
    };

    // ---- prologue: As[0,1]<-k0,k1 (DMA); Bs[0,1]<-lerp(k0,k1);
    //      crC,crD <- tap-0 quarters 2,3; offv = offp[1].
    float wgc[4], wgn[4];
    int   ixc[4], ixn[4];
    uint4 crA[4], crB[4], crC[4], crD[4];
    float2 offv;
    {
        float2 o0 = offp[0];
        setup2(o0, 0, wgc, ixc);
        dmaA(0, 0);
        dmaA(1, 1);
        SB();
        loadc(crA, ixc, 0);
        loadc(crB, ixc, 1);
        SB();
        lerpB(0, crA, wgc);   // wait on crA drains both DMAs (vmcnt FIFO)
        lerpB(1, crB, wgc);
        SB();
        loadc(crC, ixc, 2);
        loadc(crD, ixc, 3);
        offv = offp[1];
        SYNC();
    }

    // ---- main loop: tap t = 0..8, two supersteps per tap.
#pragma unroll 1
    for (int t = 0; t < 9; ++t) {
        const int kb = t * 4;
        const bool more = (t < 8);
        bf16x8 af[2][2], bfr[4][2];

        // ======== superstep A: mma k(kb) [bufs 0], k(kb+1) [bufs 1] ========
        VM8();                               // drain DMA of As[0,1]
        frag_read(0, 0, af, bfr);
        SB();
        dmaA(2, kb + 2);
        dmaA(3, kb + 3);
        SB();
        if (more) setup2(offv, t + 1, wgn, ixn);
        SB();
        lerpB(2, crC, wgc);                  // tap t, quarter 2
        lerpB(3, crD, wgc);                  // tap t, quarter 3
        SB();
        frag_mma(af, bfr);
        SB();
        frag_read(1, 1, af, bfr);
        SB();
        if (more) {
            loadc(crA, ixn, 0);              // tap t+1, quarter 0
            loadc(crB, ixn, 1);              // tap t+1, quarter 1
        }
        SB();
        frag_mma(af, bfr);
        SYNC();

        // ======== superstep B: mma k(kb+2) [bufs 2], k(kb+3) [bufs 3] ======
        if (more) { VM8(); } else { VM0(); } // t=8: only the 8 DMAs outstanding
        frag_read(2, 2, af, bfr);
        SB();
        if (more) {
            dmaA(0, kb + 4);
            dmaA(1, kb + 5);
            SB();
            lerpB(0, crA, wgn);              // tap t+1, quarter 0
            lerpB(1, crB, wgn);              // tap t+1, quarter 1
        }
        SB();
        frag_mma(af, bfr);
        SB();
        frag_read(3, 3, af, bfr);
        SB();
        if (more) {
            loadc(crC, ixn, 2);              // tap t+1, quarter 2
            loadc(crD, ixn, 3);              // tap t+1, quarter 3
            if (t < 7) offv = offp[t + 2];
#pragma unroll
            for (int c2 = 0; c2 < 4; ++c2) wgc[c2] = wgn[c2];
        }
        SB();
        frag_mma(af, bfr);
        if (more) SYNC();                    // last superstep: no barrier
    }

    // ---- epilogue: D layout col = lane&15, row = quad*4 + reg
    float* opnt = out + (size_t)n * COUT * HW + hw0;
#pragma unroll
    for (int mi = 0; mi < 2; ++mi)
#pragma unroll
        for (int ni = 0; ni < 4; ++ni) {
            int col = ni * 16 + l15;
#pragma unroll
            for (int rr = 0; rr < 4; ++rr) {
                int row = wv * 32 + mi * 16 + quad * 4 + rr;
                opnt[(size_t)row * HW + col] = acc[mi][ni][rr];
            }
        }
}

// --------------------------------------------------------------- launch ----
extern "C" void kernel_launch(void* const* d_in, const int* in_sizes, int n_in,
                              void* d_out, int out_size, void* d_ws, size_t ws_size,
                              hipStream_t stream) {
    const float* x   = (const float*)d_in[0];   // [16][256][32][32]
    const float* off = (const float*)d_in[1];   // [16][1024][18]
    const float* wt  = (const float*)d_in[2];   // [256][256][3][3]
    float* out = (float*)d_out;                 // [16][256][32][32]

    unsigned short* wbf = (unsigned short*)d_ws;                        // 1179648 B
    unsigned short* xtb = (unsigned short*)((char*)d_ws + 1179648);     // 8388608 B

    prep_kernel<<<1280, 256, 0, stream>>>(wt, wbf, x, xtb);
    fused_kernel<<<256, 512, 0, stream>>>(wbf, xtb, off, out);
}

// Round 11
// 110.621 us; speedup vs baseline: 1.0923x; 1.0441x over previous
//
#include <hip/hip_runtime.h>

// Problem constants
#define NB   16
#define CIN  256
#define COUT 256
#define HH   32
#define WW   32
#define HW   1024           // 32*32
#define KK   9
#define CK   2304           // CIN*KK  (ordered k*256 + c, tap-major)

typedef __bf16 bf16x8 __attribute__((ext_vector_type(8)));
typedef float  f32x4  __attribute__((ext_vector_type(4)));

__device__ __forceinline__ unsigned short f2bf(float f) {
    unsigned int u = __float_as_uint(f);
    u += 0x7FFFu + ((u >> 16) & 1u);          // round-nearest-even
    return (unsigned short)(u >> 16);
}
__device__ __forceinline__ float bfhi(unsigned int u) {   // high bf16 -> f32
    return __uint_as_float(u & 0xFFFF0000u);
}
__device__ __forceinline__ float bflo(unsigned int u) {   // low bf16 -> f32
    return __uint_as_float(u << 16);
}
// pack two f32 -> one dword of 2x bf16 (RNE). No builtin on gfx950 (ROCm 7.2)
// — inline asm v_cvt_pk_bf16_f32: src0 -> low 16, src1 -> high 16.
__device__ __forceinline__ unsigned pk2(float lo, float hi) {
    unsigned r;
    asm("v_cvt_pk_bf16_f32 %0, %1, %2" : "=v"(r) : "v"(lo), "v"(hi));
    return r;
}

typedef const __attribute__((address_space(1))) void* gas_ptr;
typedef __attribute__((address_space(3))) void* las_ptr;

__device__ __forceinline__ void async16(const void* g, void* l) {
    __builtin_amdgcn_global_load_lds((gas_ptr)g, (las_ptr)l, 16, 0, 0);
}

#define SB() __builtin_amdgcn_sched_barrier(0)
// Raw barrier: LDS-visibility only. vmcnt is deliberately NOT drained —
// A-DMA completion is enforced by vmcnt FIFO order (the lerp's wait on the
// younger corner-gather loads implies the older DMAs are done).
#define SYNC() do { SB(); asm volatile("s_waitcnt lgkmcnt(0)" ::: "memory"); SB(); \
                    __builtin_amdgcn_s_barrier(); SB(); } while (0)

// ----------------------------------------------------------------- prep ----
// One kernel, two roles (saves a launch and runs them concurrently):
//   blocks [0,256):    weight fp32 [O][C][3][3] -> bf16 [O][k*256+c]
//   blocks [256,1280): x fp32 [n][c][hw] -> xtb bf16 [n][hw][c] (64x64 tiles)
// Grid-barrier mono fusion measured WORSE (round 3: agent-fence L2
// invalidation costs ~100 us of gather latency) — keep two dispatches.
__global__ __launch_bounds__(256) void prep_kernel(const float* __restrict__ w,
                                                   unsigned short* __restrict__ wbf,
                                                   const float* __restrict__ x,
                                                   unsigned short* __restrict__ xtb) {
    __shared__ float lsbuf[64 * 65];
    const int t = threadIdx.x;

    if (blockIdx.x < 256) {
        // ---- wconv role
        const int o = blockIdx.x;
        const float* wo = w + (size_t)o * CK;
#pragma unroll
        for (int i = t; i < CK; i += 256) lsbuf[i] = wo[i];
        __syncthreads();
        unsigned short* dst = wbf + (size_t)o * CK;
#pragma unroll
        for (int i = t; i < CK; i += 256) {
            int k = i >> 8, c = i & 255;
            dst[i] = f2bf(lsbuf[c * KK + k]);     // bank stride 9: conflict-free
        }
        return;
    }

    // ---- xt role
    float (*ls)[65] = (float(*)[65])lsbuf;
    const int id  = blockIdx.x - 256;
    const int c0  = (id & 3) << 6;
    const int hw0 = ((id >> 2) & 15) << 6;
    const int n   = id >> 6;
    {
        int c = t >> 2, q = t & 3;
        const float4* base = (const float4*)(x + ((size_t)(n * CIN + c0 + c)) * HW + hw0 + q * 16);
#pragma unroll
        for (int j = 0; j < 4; ++j) {
            float4 v = base[j];
            ls[c][q * 16 + j * 4 + 0] = v.x;
            ls[c][q * 16 + j * 4 + 1] = v.y;
            ls[c][q * 16 + j * 4 + 2] = v.z;
            ls[c][q * 16 + j * 4 + 3] = v.w;
        }
    }
    __syncthreads();
    {
        int hw = t >> 2, seg = (t & 3) * 16;
        unsigned int dw[8];
#pragma unroll
        for (int j = 0; j < 8; ++j) {
            float f0 = ls[seg + 2 * j][hw];
            float f1 = ls[seg + 2 * j + 1][hw];
            dw[j] = (unsigned)f2bf(f0) | ((unsigned)f2bf(f1) << 16);
        }
        uint4* dst = (uint4*)(xtb + ((size_t)(n * HW + hw0 + hw)) * CIN + c0 + seg);
        dst[0] = *(uint4*)&dw[0];
        dst[1] = *(uint4*)&dw[4];
    }
}

// ---------------------------------------------------------------- fused ----
// ROUND-6 STRUCTURE (best measured: fused 41.6 us, 0 bank conflicts).
// BM=256, BN=64, BK=64, 512 thr / 8 waves, wave tile 32(o) x 64(hw).
// As triple-buffered (DMA 2 steps ahead; completion via vmcnt FIFO order —
// never drained at barriers); Bs double-buffered, lerped one step ahead
// from prefetched corner regs. Raw barrier (lgkmcnt(0)+s_barrier).
// Frag ds_reads issued FIRST in each step (they depend only on the
// barrier); DMA/lerp/gather issue under the read shadow; MFMA last with
// compiler-placed lgkmcnt waits. setprio(1) around the MFMA cluster.
//
// Design-space verdicts (measured): BK=128 -> 3.5-4.1M LDS bank conflicts
// (256 B rows; abandoned). A-frags global->VGPR -> +9 us exposed L2
// latency (abandoned). 2-kblock superstep, 18 barriers -> +2.7 us (longer
// serial chain per barrier; abandoned). This structure is the optimum.
//
// Round-11 micro-polish: offp[tap+1] prefetch moved from q2-head to q1-tail
// — a full step (~1150 cyc) of latency cover instead of ~150 cyc.
__global__ __launch_bounds__(512, 2) void fused_kernel(const unsigned short* __restrict__ wbf,
                                                       const unsigned short* __restrict__ xtb,
                                                       const float* __restrict__ off,
                                                       float* __restrict__ out) {
    __shared__ unsigned short As[3][256 * 64];   // 96 KB (triple buffer)
    __shared__ unsigned short Bs[2][64 * 64];    // 16 KB

    const int tid  = threadIdx.x;
    const int wv   = tid >> 6;                // 0..7  (M position, 32 rows each)
    const int lane = tid & 63;
    const int quad = lane >> 4;
    const int l15  = lane & 15;

    const int hw_local = tid >> 3;            // 0..63
    const int seg      = tid & 7;             // 8-channel segment within 64

    // XCD-aware decode (gfx950 dispatch: consecutive ids round-robin XCDs)
    const int id  = blockIdx.x;
    const int n   = ((id & 7) << 1) | ((id >> 3) & 1);
    const int hw0 = (id >> 4) * 64;

    const int hw = hw0 + hw_local;
    const int h  = hw >> 5, w = hw & 31;

    // A staging lane pattern (XOR swizzle encoded in source address)
    const int srow   = lane >> 3;
    const int schunk = (lane & 7) ^ (srow & 7);

    const uint4*  xb4  = (const uint4*)(xtb + (size_t)n * HW * CIN);
    const float2* offp = (const float2*)(off + ((size_t)n * HW + hw) * (2 * KK));

    f32x4 acc[2][4] = {};

    auto setup2 = [&](float2 o, int tapv, float* wg, int* ix) {
        float py = (float)(h + tapv / 3 - 1) + o.x;
        float px = (float)(w + tapv % 3 - 1) + o.y;
        float y0f = floorf(py), x0f = floorf(px);
        float ly = py - y0f, lx = px - x0f;
        int y0 = (int)y0f, x0 = (int)x0f;
#pragma unroll
        for (int c2 = 0; c2 < 4; ++c2) {
            int yy = y0 + (c2 >> 1);
            int xx = x0 + (c2 & 1);
            float wy = (c2 >> 1) ? ly : 1.0f - ly;
            float wx = (c2 & 1) ? lx : 1.0f - lx;
            bool v = (yy >= 0) && (yy < HH) && (xx >= 0) && (xx < WW);
            wg[c2] = v ? wy * wx : 0.0f;
            int yc = yy < 0 ? 0 : (yy > HH - 1 ? HH - 1 : yy);
            int xc = xx < 0 ? 0 : (xx > WW - 1 ? WW - 1 : xx);
            ix[c2] = yc * WW + xc;
        }
    };

    auto loadc = [&](uint4 cr[4], const int* ix, int q) {
#pragma unroll
        for (int c2 = 0; c2 < 4; ++c2)
            cr[c2] = xb4[(size_t)ix[c2] * 32 + q * 8 + seg];
    };

    // DMA one 256x64 A tile (kblock kblk) into As[ai]
    auto dmaA = [&](int ai, int kblk) {
        const unsigned short* wsrc = wbf + (size_t)kblk * 64 + (size_t)srow * CK + schunk * 8;
        unsigned short* dst = &As[ai][0];
#pragma unroll
        for (int j = 0; j < 4; ++j) {
            int rb = wv * 32 + j * 8;
            async16(wsrc + (size_t)rb * CK, dst + rb * 64);
        }
    };

    auto lerpB = [&](int bi, const uint4 cr[4], const float* wg) {
        unsigned u0[4], u1[4], u2[4], u3[4];
        *(uint4*)u0 = cr[0]; *(uint4*)u1 = cr[1];
        *(uint4*)u2 = cr[2]; *(uint4*)u3 = cr[3];
        unsigned dw[4];
#pragma unroll
        for (int d = 0; d < 4; ++d) {
            float lo = wg[0] * bflo(u0[d]) + wg[1] * bflo(u1[d])
                     + wg[2] * bflo(u2[d]) + wg[3] * bflo(u3[d]);
            float hi = wg[0] * bfhi(u0[d]) + wg[1] * bfhi(u1[d])
                     + wg[2] * bfhi(u2[d]) + wg[3] * bfhi(u3[d]);
            dw[d] = pk2(lo, hi);              // v_cvt_pk_bf16_f32 (RNE)
        }
        *(uint4*)&Bs[bi][hw_local * 64 + (seg ^ (hw_local & 7)) * 8] = *(uint4*)dw;
    };

    // issue the 12 frag ds_reads (no waits here; compiler places lgkmcnt
    // right before the MFMA uses)
    auto frag_read = [&](int ai, int bi, bf16x8 af[2][2], bf16x8 bfr[4][2]) {
        const unsigned short* Ap = &As[ai][0];
        const unsigned short* Bp = &Bs[bi][0];
#pragma unroll
        for (int mi = 0; mi < 2; ++mi)
#pragma unroll
            for (int hh = 0; hh < 2; ++hh) {
                int row = wv * 32 + mi * 16 + l15;
                int ch  = (hh * 4 + quad) ^ (row & 7);
                af[mi][hh] = *(const bf16x8*)(Ap + row * 64 + ch * 8);
            }
#pragma unroll
        for (int ni = 0; ni < 4; ++ni)
#pragma unroll
            for (int hh = 0; hh < 2; ++hh) {
                int row = ni * 16 + l15;
                int ch  = (hh * 4 + quad) ^ (row & 7);
                bfr[ni][hh] = *(const bf16x8*)(Bp + row * 64 + ch * 8);
            }
    };

    auto frag_mma = [&](bf16x8 af[2][2], bf16x8 bfr[4][2]) {
        __builtin_amdgcn_s_setprio(1);
#pragma unroll
        for (int mi = 0; mi < 2; ++mi)
#pragma unroll
            for (int ni = 0; ni < 4; ++ni) {
                acc[mi][ni] = __builtin_amdgcn_mfma_f32_16x16x32_bf16(af[mi][0], bfr[ni][0], acc[mi][ni], 0, 0, 0);
                acc[mi][ni] = __builtin_amdgcn_mfma_f32_16x16x32_bf16(af[mi][1], bfr[ni][1], acc[mi][ni], 0, 0, 0);
            }
        __builtin_amdgcn_s_setprio(0);
    };

    // ---- prologue: As[0]<-k0, As[1]<-k1 (DMA), Bs[0]<-lerp(k0), crB holds k1
    float wgc[4], wgn[4];
    int   ixc[4], ixn[4];
    uint4 crA[4], crB[4];
    {
        float2 o0 = offp[0];
        setup2(o0, 0, wgc, ixc);
        dmaA(0, 0);
        dmaA(1, 1);
        SB();
        loadc(crA, ixc, 0);
        loadc(crB, ixc, 1);
        SB();
        lerpB(0, crA, wgc);   // compiler wait on crA drains both DMAs (FIFO)
        SYNC();
    }

    // ---- main loop: step s = tap*4+q. mfma reads As[s%3], Bs[s%2].
    // DMA at step s targets As[(s+2)%3] with kblock s+2.
    int i0 = 0;                               // == (tap*4) % 3
#pragma unroll 1
    for (int tap = 0; tap < 9; ++tap) {
        const int i1 = (i0 == 2) ? 0 : i0 + 1;
        const int i2 = (i1 == 2) ? 0 : i1 + 1;
        const int kb = tap * 4;
        const bool more = (tap < 8);
        bf16x8 af[2][2], bfr[4][2];
        float2 onx = {};

        // q0: reads(i0,B0) | dma k(kb+2)->As[i2] | lerp k(kb+1)->Bs[1]
        //     | loadc k(kb+2) | mfma
        frag_read(i0, 0, af, bfr);
        SB();
        dmaA(i2, kb + 2);
        SB();
        lerpB(1, crB, wgc);
        SB();
        loadc(crA, ixc, 2);
        SB();
        frag_mma(af, bfr);
        SYNC();

        // q1: reads(i1,B1) | dma k(kb+3)->As[i0] | lerp k(kb+2)->Bs[0]
        //     | loadc k(kb+3) | offp prefetch (consumed next step) | mfma
        frag_read(i1, 1, af, bfr);
        SB();
        dmaA(i0, kb + 3);
        SB();
        lerpB(0, crA, wgc);
        SB();
        loadc(crB, ixc, 3);
        if (more) onx = offp[tap + 1];       // full-step latency cover
        SB();
        frag_mma(af, bfr);
        SYNC();

        // q2: reads(i2,B0) | dma k(kb+4)->As[i1] | lerp k(kb+3)->Bs[1]
        //     | setup+loadc k(kb+4) | mfma
        frag_read(i2, 0, af, bfr);
        SB();
        if (more) dmaA(i1, kb + 4);
        SB();
        lerpB(1, crB, wgc);
        SB();
        if (more) { setup2(onx, tap + 1, wgn, ixn); loadc(crA, ixn, 0); }
        SB();
        frag_mma(af, bfr);
        SYNC();

        // q3: reads(i0,B1) | dma k(kb+5)->As[i2] | lerp k(kb+4)->Bs[0]
        //     (new tap!) | loadc k(kb+5) | mfma
        frag_read(i0, 1, af, bfr);
        SB();
        if (more) {
            dmaA(i2, kb + 5);
            SB();
            lerpB(0, crA, wgn);
            SB();
            loadc(crB, ixn, 1);
#pragma unroll
            for (int c2 = 0; c2 < 4; ++c2) { wgc[c2] = wgn[c2]; ixc[c2] = ixn[c2]; }
            SB();
            frag_mma(af, bfr);
            SYNC();
        } else {
            frag_mma(af, bfr);       // last step, no barrier needed after
        }
        i0 = i1;
    }

    // ---- epilogue: D layout col = lane&15, row = quad*4 + reg
    float* opnt = out + (size_t)n * COUT * HW + hw0;
#pragma unroll
    for (int mi = 0; mi < 2; ++mi)
#pragma unroll
        for (int ni = 0; ni < 4; ++ni) {
            int col = ni * 16 + l15;
#pragma unroll
            for (int rr = 0; rr < 4; ++rr) {
                int row = wv * 32 + mi * 16 + quad * 4 + rr;
                opnt[(size_t)row * HW + col] = acc[mi][ni][rr];
            }
        }
}

// --------------------------------------------------------------- launch ----
extern "C" void kernel_launch(void* const* d_in, const int* in_sizes, int n_in,
                              void* d_out, int out_size, void* d_ws, size_t ws_size,
                              hipStream_t stream) {
    const float* x   = (const float*)d_in[0];   // [16][256][32][32]
    const float* off = (const float*)d_in[1];   // [16][1024][18]
    const float* wt  = (const float*)d_in[2];   // [256][256][3][3]
    float* out = (float*)d_out;                 // [16][256][32][32]

    unsigned short* wbf = (unsigned short*)d_ws;                        // 1179648 B
    unsigned short* xtb = (unsigned short*)((char*)d_ws + 1179648);     // 8388608 B

    prep_kernel<<<1280, 256, 0, stream>>>(wt, wbf, x, xtb);
    fused_kernel<<<256, 512, 0, stream>>>(wbf, xtb, off, out);
}